// Round 11
// baseline (131.054 us; speedup 1.0000x reference)
//
#include <hip/hip_runtime.h>
#include <hip/hip_fp16.h>
#include <math.h>

#define IDIM 160
#define GDIM 161
#define GDIM2 (GDIM * GDIM)         // 25921
#define NB_SAMPLES 64
#define NB_RAYS 32768
#define NCELL (GDIM * GDIM * GDIM)  // 4173281
#define ZT 11                        // ceil(161/16) tiles in z
#define YT 11                        // ceil(161/16) tiles in y

typedef unsigned uint4n __attribute__((ext_vector_type(4)));  // native vec for nontemporal builtins

// ---------------- Threefry2x32 (JAX-compatible, partitionable path) ----------------
__device__ __forceinline__ unsigned rotl32(unsigned x, unsigned d) {
    return (x << d) | (x >> (32u - d));
}

__device__ __forceinline__ void tf_round(unsigned& x0, unsigned& x1, unsigned r) {
    x0 += x1;
    x1 = rotl32(x1, r);
    x1 ^= x0;
}

__device__ __forceinline__ unsigned jax_random_bits(unsigned idx) {
    const unsigned k0 = 0u, k1 = 42u;
    const unsigned ks2 = k0 ^ k1 ^ 0x1BD11BDAu;
    unsigned x0 = 0u + k0;    // counts_hi + ks0
    unsigned x1 = idx + k1;   // counts_lo + ks1
    tf_round(x0, x1, 13); tf_round(x0, x1, 15); tf_round(x0, x1, 26); tf_round(x0, x1, 6);
    x0 += k1;  x1 += ks2 + 1u;
    tf_round(x0, x1, 17); tf_round(x0, x1, 29); tf_round(x0, x1, 16); tf_round(x0, x1, 24);
    x0 += ks2; x1 += k0 + 2u;
    tf_round(x0, x1, 13); tf_round(x0, x1, 15); tf_round(x0, x1, 26); tf_round(x0, x1, 6);
    x0 += k0;  x1 += k1 + 3u;
    tf_round(x0, x1, 17); tf_round(x0, x1, 29); tf_round(x0, x1, 16); tf_round(x0, x1, 24);
    x0 += k1;  x1 += ks2 + 4u;
    tf_round(x0, x1, 13); tf_round(x0, x1, 15); tf_round(x0, x1, 26); tf_round(x0, x1, 6);
    x0 += ks2; x1 += k0 + 5u;
    return x0 ^ x1;
}

// fp16x2 (packed in u32) -> float2
__device__ __forceinline__ float2 h2f2(unsigned u) {
    const __half2 h = *(const __half2*)&u;
    return __half22float2(h);
}

__device__ __forceinline__ unsigned pack_ho(float s, float op) {
    const unsigned hs = (unsigned)__half_as_ushort(__float2half(s));
    const unsigned ho = (unsigned)__half_as_ushort(__float2half(op));
    return hs | (ho << 16);
}

// Nontemporal cell pack: stream grid+opac through without L2 allocation.
__device__ __forceinline__ unsigned cell_pack_nt(const float* __restrict__ grid,
                                                 const float* __restrict__ opac, int i) {
    const float* g = grid + (size_t)i * 9;
    float s = 0.0f;
#pragma unroll
    for (int c = 0; c < 9; ++c) s += __builtin_nontemporal_load(&g[c]);
    return pack_ho(s, __builtin_nontemporal_load(&opac[i]));
}

// ---------------- Fused prep: grid -> quad table in ONE pass (nontemporal I/O).
// Block = one 16x16 (y,z) tile of one x-slab. LDS holds the 17x17 halo of
// packed cell values; each thread then emits one uint4 entry
// (vv[y][z], vv[y][z+1], vv[y+1][z], vv[y+1][z+1]).
// Entries at y==160 or z==160 are never read by main (base clipped <=159);
// halo clamps keep all reads in bounds.
__global__ __launch_bounds__(256) void rf_fused(const float* __restrict__ grid,
                                                const float* __restrict__ opac,
                                                unsigned* __restrict__ pk) {
    __shared__ unsigned vv[17][18];  // +1 pad column to de-stripe banks
    const int t = threadIdx.x;
    const int bz = blockIdx.x % ZT;
    const int by = (blockIdx.x / ZT) % YT;
    const int x  = blockIdx.x / (ZT * YT);
    const int z0 = bz * 16, y0 = by * 16;

    // load 17x17 halo cells (threads 0..32 do a second cell)
    for (int idx = t; idx < 289; idx += 256) {
        const int cy = idx / 17, cz = idx % 17;
        const int y = min(y0 + cy, GDIM - 1);
        const int z = min(z0 + cz, GDIM - 1);
        const int ci = (x * GDIM + y) * GDIM + z;
        vv[cy][cz] = cell_pack_nt(grid, opac, ci);
    }
    __syncthreads();

    const int ty = t >> 4, tz = t & 15;
    const int y = y0 + ty, z = z0 + tz;
    if (y < GDIM && z < GDIM) {
        const int e = (x * GDIM + y) * GDIM + z;
        uint4n q;
        q.x = vv[ty][tz];
        q.y = vv[ty][tz + 1];
        q.z = vv[ty + 1][tz];
        q.w = vv[ty + 1][tz + 1];
        __builtin_nontemporal_store(q, (uint4n*)(pk + (size_t)e * 4));
    }
}

// ---------------- Main: one 64-lane wave per ray, one lane per sample ----------------
// MODE: 0 = fused-read (grid directly), 2 = quad fp16 table
template <int MODE>
__global__ __launch_bounds__(256) void rf_main(const float* __restrict__ x,
                                               const float* __restrict__ d,
                                               const void* __restrict__ table,
                                               const float* __restrict__ grid,
                                               const float* __restrict__ opac,
                                               float* __restrict__ out) {
    const int lane = threadIdx.x & 63;
    const int ray = blockIdx.x * (blockDim.x >> 6) + (threadIdx.x >> 6);
    if (ray >= NB_RAYS) return;

    const float ox = x[ray * 3 + 0], oy = x[ray * 3 + 1], oz = x[ray * 3 + 2];
    const float dx = d[ray * 3 + 0], dy = d[ray * 3 + 1], dz = d[ray * 3 + 2];
    const float ivx = 1.0f / dx, ivy = 1.0f / dy, ivz = 1.0f / dz;

    const float INF0 = (float)IDIM * (float)IDIM * (float)IDIM;  // 4096000
    float tmin = -INF0, tmax = INF0;
    {
        float t0 = (0.0f - ox) * ivx, t1 = ((float)IDIM - ox) * ivx;
        tmin = fmaxf(tmin, fminf(t0, t1));
        tmax = fminf(tmax, fmaxf(t0, t1));
        t0 = (0.0f - oy) * ivy; t1 = ((float)IDIM - oy) * ivy;
        tmin = fmaxf(tmin, fminf(t0, t1));
        tmax = fminf(tmax, fmaxf(t0, t1));
        t0 = (0.0f - oz) * ivz; t1 = ((float)IDIM - oz) * ivz;
        tmin = fmaxf(tmin, fminf(t0, t1));
        tmax = fminf(tmax, fmaxf(t0, t1));
    }

    // u via threefry, sample position
    const unsigned flat = (unsigned)ray * 64u + (unsigned)lane;
    const unsigned bits = jax_random_bits(flat);
    const float u = __uint_as_float((bits >> 9) | 0x3f800000u) - 1.0f;
    float t = tmin + u * (tmax - tmin);

    // Bitonic sort ascending across the 64 lanes of the wave
#pragma unroll
    for (int k = 2; k <= 64; k <<= 1) {
#pragma unroll
        for (int j = k >> 1; j > 0; j >>= 1) {
            float p = __shfl_xor(t, j, 64);
            bool up = ((lane & k) == 0);
            bool lower = ((lane & j) == 0);
            t = (up == lower) ? fminf(t, p) : fmaxf(t, p);
        }
    }

    const float tnext = __shfl_down(t, 1, 64);  // garbage at lane 63 (masked later)

    // Sample point + trilerp setup (mirror reference: floor, clip, frac)
    const float px = ox + t * dx, py = oy + t * dy, pz = oz + t * dz;
    float bx = fminf(fmaxf(floorf(px), 0.0f), (float)(IDIM - 1));
    float by = fminf(fmaxf(floorf(py), 0.0f), (float)(IDIM - 1));
    float bz = fminf(fmaxf(floorf(pz), 0.0f), (float)(IDIM - 1));
    const int ix = (int)bx, iy = (int)by, iz = (int)bz;
    const float fx = px - bx, fy = py - by, fz = pz - bz;

    float h = 0.0f, o = 0.0f;
    if (MODE == 2) {
        const uint4* __restrict__ pkq = (const uint4*)table;
        const float wy0 = 1.0f - fy, wy1 = fy, wz0 = 1.0f - fz, wz1 = fz;
        const size_t e0 = ((size_t)ix * GDIM + (size_t)iy) * GDIM + (size_t)iz;
        const uint4 qa = pkq[e0];
        const uint4 qb = pkq[e0 + (size_t)GDIM2];
#pragma unroll
        for (int cx = 0; cx < 2; ++cx) {
            const uint4 q = cx ? qb : qa;
            const float wx = cx ? fx : 1.0f - fx;
            const float w00 = wx * wy0 * wz0, w01 = wx * wy0 * wz1;
            const float w10 = wx * wy1 * wz0, w11 = wx * wy1 * wz1;
            float2 f;
            f = h2f2(q.x); h += w00 * f.x; o += w00 * f.y;
            f = h2f2(q.y); h += w01 * f.x; o += w01 * f.y;
            f = h2f2(q.z); h += w10 * f.x; o += w10 * f.y;
            f = h2f2(q.w); h += w11 * f.x; o += w11 * f.y;
        }
    } else {
#pragma unroll
        for (int c = 0; c < 8; ++c) {
            const int cx = (c >> 2) & 1, cy = (c >> 1) & 1, cz = c & 1;
            const float w = (cx ? fx : 1.0f - fx) * (cy ? fy : 1.0f - fy) * (cz ? fz : 1.0f - fz);
            const size_t idx = ((size_t)(ix + cx) * GDIM + (size_t)(iy + cy)) * GDIM + (size_t)(iz + cz);
            const float* g = grid + idx * 9;
            float s = 0.0f;
#pragma unroll
            for (int ch = 0; ch < 9; ++ch) s += g[ch];
            h += w * s;
            o += w * opac[idx];
        }
    }

    // Transmittance accumulation across the wave
    const float delta = tnext - t;
    const float cur = (lane < 63) ? delta * o : 0.0f;

    float inc = cur;  // inclusive prefix sum
#pragma unroll
    for (int off = 1; off < 64; off <<= 1) {
        float n = __shfl_up(inc, off, 64);
        if (lane >= off) inc += n;
    }
    const float excl = inc - cur;
    const float trans = expf(-excl);
    const float colr = 1.0f / (1.0f + expf(-h));
    float contrib = (lane < 63) ? trans * (1.0f - expf(-cur)) * colr : 0.0f;

#pragma unroll
    for (int off = 32; off > 0; off >>= 1) contrib += __shfl_xor(contrib, off, 64);

    if (lane == 0) out[ray] = contrib;
}

extern "C" void kernel_launch(void* const* d_in, const int* in_sizes, int n_in,
                              void* d_out, int out_size, void* d_ws, size_t ws_size,
                              hipStream_t stream) {
    const float* x = (const float*)d_in[0];
    const float* d = (const float*)d_in[1];
    const float* grid = (const float*)d_in[2];
    const float* opac = (const float*)d_in[3];
    float* out = (float*)d_out;

    const size_t need_quad = (size_t)NCELL * 16;  // ~66.8 MB
    const int waves_per_block = 4;  // 256 threads
    const int nblocks = NB_RAYS / waves_per_block;
    const int fused_blocks = ZT * YT * GDIM;      // 11*11*161 = 19481

    if (ws_size >= need_quad) {
        unsigned* pk = (unsigned*)d_ws;
        rf_fused<<<fused_blocks, 256, 0, stream>>>(grid, opac, pk);
        rf_main<2><<<nblocks, 256, 0, stream>>>(x, d, pk, nullptr, nullptr, out);
    } else {
        rf_main<0><<<nblocks, 256, 0, stream>>>(x, d, nullptr, grid, opac, out);
    }
}

// Round 12
// 107.381 us; speedup vs baseline: 1.2205x; 1.2205x over previous
//
#include <hip/hip_runtime.h>
#include <hip/hip_fp16.h>
#include <math.h>

#define IDIM 160
#define GDIM 161
#define GDIM2 (GDIM * GDIM)         // 25921
#define NB_SAMPLES 64
#define NB_RAYS 32768
#define NCELL (GDIM * GDIM * GDIM)  // 4173281
#define NQUAD (NCELL / 4)           // 1043320 full 4-entry chunks (+1 tail entry)

// ---------------- Threefry2x32 (JAX-compatible, partitionable path) ----------------
__device__ __forceinline__ unsigned rotl32(unsigned x, unsigned d) {
    return (x << d) | (x >> (32u - d));
}

__device__ __forceinline__ void tf_round(unsigned& x0, unsigned& x1, unsigned r) {
    x0 += x1;
    x1 = rotl32(x1, r);
    x1 ^= x0;
}

__device__ __forceinline__ unsigned jax_random_bits(unsigned idx) {
    const unsigned k0 = 0u, k1 = 42u;
    const unsigned ks2 = k0 ^ k1 ^ 0x1BD11BDAu;
    unsigned x0 = 0u + k0;    // counts_hi + ks0
    unsigned x1 = idx + k1;   // counts_lo + ks1
    tf_round(x0, x1, 13); tf_round(x0, x1, 15); tf_round(x0, x1, 26); tf_round(x0, x1, 6);
    x0 += k1;  x1 += ks2 + 1u;
    tf_round(x0, x1, 17); tf_round(x0, x1, 29); tf_round(x0, x1, 16); tf_round(x0, x1, 24);
    x0 += ks2; x1 += k0 + 2u;
    tf_round(x0, x1, 13); tf_round(x0, x1, 15); tf_round(x0, x1, 26); tf_round(x0, x1, 6);
    x0 += k0;  x1 += k1 + 3u;
    tf_round(x0, x1, 17); tf_round(x0, x1, 29); tf_round(x0, x1, 16); tf_round(x0, x1, 24);
    x0 += k1;  x1 += ks2 + 4u;
    tf_round(x0, x1, 13); tf_round(x0, x1, 15); tf_round(x0, x1, 26); tf_round(x0, x1, 6);
    x0 += ks2; x1 += k0 + 5u;
    return x0 ^ x1;
}

// fp16x2 (packed in u32) -> float2
__device__ __forceinline__ float2 h2f2(unsigned u) {
    const __half2 h = *(const __half2*)&u;
    return __half22float2(h);
}

__device__ __forceinline__ unsigned pack_ho(float s, float op) {
    const unsigned hs = (unsigned)__half_as_ushort(__float2half(s));
    const unsigned ho = (unsigned)__half_as_ushort(__float2half(op));
    return hs | (ho << 16);
}

// ---------------- Pass A: per-cell packed fp16 (h_sum, opacity), u32 per cell.
// One thread per cell, scalar 9-float row read (R1-proven ~31us incl. write),
// coalesced 4B store. No LDS, no barrier, no dual-role threads.
__global__ __launch_bounds__(256) void rf_cells(const float* __restrict__ grid,
                                                const float* __restrict__ opac,
                                                unsigned* __restrict__ v) {
    const int i = blockIdx.x * blockDim.x + threadIdx.x;
    if (i >= NCELL) return;
    const float* g = grid + (size_t)i * 9;
    float s = 0.0f;
#pragma unroll
    for (int c = 0; c < 9; ++c) s += g[c];
    v[i] = pack_ho(s, opac[i]);
}

// ---------------- Pass B (batched x4): entries 4j..4j+3 per thread.
// Entry e = {v[e], v[e+1], v[e+GDIM], v[e+GDIM+1]}.
// a[0..4] = v[e0..e0+4]            (uint4 + dword, 16B-aligned)
// B8[0..7] = v[e0+160..e0+167]     (two aligned uint4) -> b[i] = B8[1+i]
// Entries whose windows would clamp are only those with x==160 / y==160 /
// z==160, which rf_main never reads (base indices clipped to <=159).
__global__ __launch_bounds__(256) void rf_quad4(const unsigned* __restrict__ v,
                                                uint4* __restrict__ pk) {
    const int j = blockIdx.x * blockDim.x + threadIdx.x;
    const int m = NCELL - 1;
    if (j < NQUAD) {
        const int e0 = j * 4;                 // e0+4 <= NQUAD*4 = m, always in bounds
        unsigned a[5];
        *(uint4*)a = *(const uint4*)(v + e0); // aligned: e0 % 4 == 0
        a[4] = v[e0 + 4];

        unsigned b[5];
        if (e0 + 167 <= m) {                  // fast path: aligned dual-x4 window
            uint4 lo = *(const uint4*)(v + e0 + 160);
            uint4 hi = *(const uint4*)(v + e0 + 164);
            b[0] = lo.y; b[1] = lo.z; b[2] = lo.w; b[3] = hi.x; b[4] = hi.y;
        } else {                              // tail blocks: clamped scalar loads
#pragma unroll
            for (int i = 0; i < 5; ++i) b[i] = v[min(e0 + GDIM + i, m)];
        }

#pragma unroll
        for (int i = 0; i < 4; ++i)
            pk[e0 + i] = make_uint4(a[i], a[i + 1], b[i], b[i + 1]);
    } else if (j == NQUAD) {
        // tail entry e = m
        const int e = m;
        pk[e] = make_uint4(v[e], v[min(e + 1, m)], v[min(e + GDIM, m)], v[min(e + GDIM + 1, m)]);
    }
}

// ---------------- Main: one 64-lane wave per ray, one lane per sample ----------------
// MODE: 0 = fused-read (grid directly), 2 = quad fp16 table
template <int MODE>
__global__ __launch_bounds__(256) void rf_main(const float* __restrict__ x,
                                               const float* __restrict__ d,
                                               const void* __restrict__ table,
                                               const float* __restrict__ grid,
                                               const float* __restrict__ opac,
                                               float* __restrict__ out) {
    const int lane = threadIdx.x & 63;
    const int ray = blockIdx.x * (blockDim.x >> 6) + (threadIdx.x >> 6);
    if (ray >= NB_RAYS) return;

    const float ox = x[ray * 3 + 0], oy = x[ray * 3 + 1], oz = x[ray * 3 + 2];
    const float dx = d[ray * 3 + 0], dy = d[ray * 3 + 1], dz = d[ray * 3 + 2];
    const float ivx = 1.0f / dx, ivy = 1.0f / dy, ivz = 1.0f / dz;

    const float INF0 = (float)IDIM * (float)IDIM * (float)IDIM;  // 4096000
    float tmin = -INF0, tmax = INF0;
    {
        float t0 = (0.0f - ox) * ivx, t1 = ((float)IDIM - ox) * ivx;
        tmin = fmaxf(tmin, fminf(t0, t1));
        tmax = fminf(tmax, fmaxf(t0, t1));
        t0 = (0.0f - oy) * ivy; t1 = ((float)IDIM - oy) * ivy;
        tmin = fmaxf(tmin, fminf(t0, t1));
        tmax = fminf(tmax, fmaxf(t0, t1));
        t0 = (0.0f - oz) * ivz; t1 = ((float)IDIM - oz) * ivz;
        tmin = fmaxf(tmin, fminf(t0, t1));
        tmax = fminf(tmax, fmaxf(t0, t1));
    }

    // u via threefry, sample position
    const unsigned flat = (unsigned)ray * 64u + (unsigned)lane;
    const unsigned bits = jax_random_bits(flat);
    const float u = __uint_as_float((bits >> 9) | 0x3f800000u) - 1.0f;
    float t = tmin + u * (tmax - tmin);

    // Bitonic sort ascending across the 64 lanes of the wave
#pragma unroll
    for (int k = 2; k <= 64; k <<= 1) {
#pragma unroll
        for (int j = k >> 1; j > 0; j >>= 1) {
            float p = __shfl_xor(t, j, 64);
            bool up = ((lane & k) == 0);
            bool lower = ((lane & j) == 0);
            t = (up == lower) ? fminf(t, p) : fmaxf(t, p);
        }
    }

    const float tnext = __shfl_down(t, 1, 64);  // garbage at lane 63 (masked later)

    // Sample point + trilerp setup (mirror reference: floor, clip, frac)
    const float px = ox + t * dx, py = oy + t * dy, pz = oz + t * dz;
    float bx = fminf(fmaxf(floorf(px), 0.0f), (float)(IDIM - 1));
    float by = fminf(fmaxf(floorf(py), 0.0f), (float)(IDIM - 1));
    float bz = fminf(fmaxf(floorf(pz), 0.0f), (float)(IDIM - 1));
    const int ix = (int)bx, iy = (int)by, iz = (int)bz;
    const float fx = px - bx, fy = py - by, fz = pz - bz;

    float h = 0.0f, o = 0.0f;
    if (MODE == 2) {
        const uint4* __restrict__ pkq = (const uint4*)table;
        const float wy0 = 1.0f - fy, wy1 = fy, wz0 = 1.0f - fz, wz1 = fz;
        const size_t e0 = ((size_t)ix * GDIM + (size_t)iy) * GDIM + (size_t)iz;
        const uint4 qa = pkq[e0];
        const uint4 qb = pkq[e0 + (size_t)GDIM2];
#pragma unroll
        for (int cx = 0; cx < 2; ++cx) {
            const uint4 q = cx ? qb : qa;
            const float wx = cx ? fx : 1.0f - fx;
            const float w00 = wx * wy0 * wz0, w01 = wx * wy0 * wz1;
            const float w10 = wx * wy1 * wz0, w11 = wx * wy1 * wz1;
            float2 f;
            f = h2f2(q.x); h += w00 * f.x; o += w00 * f.y;
            f = h2f2(q.y); h += w01 * f.x; o += w01 * f.y;
            f = h2f2(q.z); h += w10 * f.x; o += w10 * f.y;
            f = h2f2(q.w); h += w11 * f.x; o += w11 * f.y;
        }
    } else {
#pragma unroll
        for (int c = 0; c < 8; ++c) {
            const int cx = (c >> 2) & 1, cy = (c >> 1) & 1, cz = c & 1;
            const float w = (cx ? fx : 1.0f - fx) * (cy ? fy : 1.0f - fy) * (cz ? fz : 1.0f - fz);
            const size_t idx = ((size_t)(ix + cx) * GDIM + (size_t)(iy + cy)) * GDIM + (size_t)(iz + cz);
            const float* g = grid + idx * 9;
            float s = 0.0f;
#pragma unroll
            for (int ch = 0; ch < 9; ++ch) s += g[ch];
            h += w * s;
            o += w * opac[idx];
        }
    }

    // Transmittance accumulation across the wave
    const float delta = tnext - t;
    const float cur = (lane < 63) ? delta * o : 0.0f;

    float inc = cur;  // inclusive prefix sum
#pragma unroll
    for (int off = 1; off < 64; off <<= 1) {
        float n = __shfl_up(inc, off, 64);
        if (lane >= off) inc += n;
    }
    const float excl = inc - cur;
    const float trans = expf(-excl);
    const float colr = 1.0f / (1.0f + expf(-h));
    float contrib = (lane < 63) ? trans * (1.0f - expf(-cur)) * colr : 0.0f;

#pragma unroll
    for (int off = 32; off > 0; off >>= 1) contrib += __shfl_xor(contrib, off, 64);

    if (lane == 0) out[ray] = contrib;
}

extern "C" void kernel_launch(void* const* d_in, const int* in_sizes, int n_in,
                              void* d_out, int out_size, void* d_ws, size_t ws_size,
                              hipStream_t stream) {
    const float* x = (const float*)d_in[0];
    const float* d = (const float*)d_in[1];
    const float* grid = (const float*)d_in[2];
    const float* opac = (const float*)d_in[3];
    float* out = (float*)d_out;

    const size_t need = (size_t)NCELL * 16 + (size_t)NCELL * 4;  // quad table + v (~83.5 MB)
    const int waves_per_block = 4;  // 256 threads
    const int nblocks = NB_RAYS / waves_per_block;
    const int cell_blocks = (NCELL + 255) / 256;
    const int quad_blocks = (NQUAD + 1 + 255) / 256;

    if (ws_size >= need) {
        uint4* pk = (uint4*)d_ws;
        unsigned* v = (unsigned*)((char*)d_ws + (size_t)NCELL * 16);
        rf_cells<<<cell_blocks, 256, 0, stream>>>(grid, opac, v);
        rf_quad4<<<quad_blocks, 256, 0, stream>>>(v, pk);
        rf_main<2><<<nblocks, 256, 0, stream>>>(x, d, pk, nullptr, nullptr, out);
    } else {
        rf_main<0><<<nblocks, 256, 0, stream>>>(x, d, nullptr, grid, opac, out);
    }
}

// Round 13
// 105.023 us; speedup vs baseline: 1.2479x; 1.0225x over previous
//
#include <hip/hip_runtime.h>
#include <hip/hip_fp16.h>
#include <math.h>

#define IDIM 160
#define GDIM 161
#define GDIM2 (GDIM * GDIM)         // 25921
#define NB_SAMPLES 64
#define NB_RAYS 32768
#define NCELL (GDIM * GDIM * GDIM)  // 4173281
#define ZT 11                        // ceil(161/16) tiles in z
#define YT 11                        // ceil(161/16) tiles in y

typedef unsigned uint4n __attribute__((ext_vector_type(4)));  // native vec for nontemporal store

// ---------------- Threefry2x32 (JAX-compatible, partitionable path) ----------------
__device__ __forceinline__ unsigned rotl32(unsigned x, unsigned d) {
    return (x << d) | (x >> (32u - d));
}

__device__ __forceinline__ void tf_round(unsigned& x0, unsigned& x1, unsigned r) {
    x0 += x1;
    x1 = rotl32(x1, r);
    x1 ^= x0;
}

__device__ __forceinline__ unsigned jax_random_bits(unsigned idx) {
    const unsigned k0 = 0u, k1 = 42u;
    const unsigned ks2 = k0 ^ k1 ^ 0x1BD11BDAu;
    unsigned x0 = 0u + k0;    // counts_hi + ks0
    unsigned x1 = idx + k1;   // counts_lo + ks1
    tf_round(x0, x1, 13); tf_round(x0, x1, 15); tf_round(x0, x1, 26); tf_round(x0, x1, 6);
    x0 += k1;  x1 += ks2 + 1u;
    tf_round(x0, x1, 17); tf_round(x0, x1, 29); tf_round(x0, x1, 16); tf_round(x0, x1, 24);
    x0 += ks2; x1 += k0 + 2u;
    tf_round(x0, x1, 13); tf_round(x0, x1, 15); tf_round(x0, x1, 26); tf_round(x0, x1, 6);
    x0 += k0;  x1 += k1 + 3u;
    tf_round(x0, x1, 17); tf_round(x0, x1, 29); tf_round(x0, x1, 16); tf_round(x0, x1, 24);
    x0 += k1;  x1 += ks2 + 4u;
    tf_round(x0, x1, 13); tf_round(x0, x1, 15); tf_round(x0, x1, 26); tf_round(x0, x1, 6);
    x0 += ks2; x1 += k0 + 5u;
    return x0 ^ x1;
}

// fp16x2 (packed in u32) -> float2
__device__ __forceinline__ float2 h2f2(unsigned u) {
    const __half2 h = *(const __half2*)&u;
    return __half22float2(h);
}

__device__ __forceinline__ unsigned pack_ho(float s, float op) {
    const unsigned hs = (unsigned)__half_as_ushort(__float2half(s));
    const unsigned ho = (unsigned)__half_as_ushort(__float2half(op));
    return hs | (ho << 16);
}

// Normal cached loads: consecutive lanes share cache lines across the 9 scalar
// reads (36B row stride) -- caching is essential here (R11 lesson).
__device__ __forceinline__ unsigned cell_pack(const float* __restrict__ grid,
                                              const float* __restrict__ opac, int i) {
    const float* g = grid + (size_t)i * 9;
    float s = 0.0f;
#pragma unroll
    for (int c = 0; c < 9; ++c) s += g[c];
    return pack_ho(s, opac[i]);
}

// ---------------- Fused prep: grid -> quad table in ONE pass.
// Cached reads; NONTEMPORAL store of the 67MB table (write set > 32MB L2:
// normal stores thrash L2 via write-allocate -- the rocclr fill kernel's
// streaming-store idiom writes this same buffer at 7 TB/s).
// Block = one 16x16 (y,z) tile of one x-slab. LDS holds the 17x17 halo of
// packed cell values; each thread then emits one uint4 entry
// (vv[y][z], vv[y][z+1], vv[y+1][z], vv[y+1][z+1]).
// Entries at y==160 or z==160 are never read by main (base clipped <=159);
// halo clamps keep all reads in bounds.
__global__ __launch_bounds__(256) void rf_fused(const float* __restrict__ grid,
                                                const float* __restrict__ opac,
                                                unsigned* __restrict__ pk) {
    __shared__ unsigned vv[17][18];  // +1 pad column to de-stripe banks
    const int t = threadIdx.x;
    const int bz = blockIdx.x % ZT;
    const int by = (blockIdx.x / ZT) % YT;
    const int x  = blockIdx.x / (ZT * YT);
    const int z0 = bz * 16, y0 = by * 16;

    // load 17x17 halo cells (threads 0..32 do a second cell)
    for (int idx = t; idx < 289; idx += 256) {
        const int cy = idx / 17, cz = idx % 17;
        const int y = min(y0 + cy, GDIM - 1);
        const int z = min(z0 + cz, GDIM - 1);
        const int ci = (x * GDIM + y) * GDIM + z;
        vv[cy][cz] = cell_pack(grid, opac, ci);
    }
    __syncthreads();

    const int ty = t >> 4, tz = t & 15;
    const int y = y0 + ty, z = z0 + tz;
    if (y < GDIM && z < GDIM) {
        const int e = (x * GDIM + y) * GDIM + z;
        uint4n q;
        q.x = vv[ty][tz];
        q.y = vv[ty][tz + 1];
        q.z = vv[ty + 1][tz];
        q.w = vv[ty + 1][tz + 1];
        __builtin_nontemporal_store(q, (uint4n*)(pk + (size_t)e * 4));
    }
}

// ---------------- Main: one 64-lane wave per ray, one lane per sample ----------------
// MODE: 0 = fused-read (grid directly), 2 = quad fp16 table
template <int MODE>
__global__ __launch_bounds__(256) void rf_main(const float* __restrict__ x,
                                               const float* __restrict__ d,
                                               const void* __restrict__ table,
                                               const float* __restrict__ grid,
                                               const float* __restrict__ opac,
                                               float* __restrict__ out) {
    const int lane = threadIdx.x & 63;
    const int ray = blockIdx.x * (blockDim.x >> 6) + (threadIdx.x >> 6);
    if (ray >= NB_RAYS) return;

    const float ox = x[ray * 3 + 0], oy = x[ray * 3 + 1], oz = x[ray * 3 + 2];
    const float dx = d[ray * 3 + 0], dy = d[ray * 3 + 1], dz = d[ray * 3 + 2];
    const float ivx = 1.0f / dx, ivy = 1.0f / dy, ivz = 1.0f / dz;

    const float INF0 = (float)IDIM * (float)IDIM * (float)IDIM;  // 4096000
    float tmin = -INF0, tmax = INF0;
    {
        float t0 = (0.0f - ox) * ivx, t1 = ((float)IDIM - ox) * ivx;
        tmin = fmaxf(tmin, fminf(t0, t1));
        tmax = fminf(tmax, fmaxf(t0, t1));
        t0 = (0.0f - oy) * ivy; t1 = ((float)IDIM - oy) * ivy;
        tmin = fmaxf(tmin, fminf(t0, t1));
        tmax = fminf(tmax, fmaxf(t0, t1));
        t0 = (0.0f - oz) * ivz; t1 = ((float)IDIM - oz) * ivz;
        tmin = fmaxf(tmin, fminf(t0, t1));
        tmax = fminf(tmax, fmaxf(t0, t1));
    }

    // u via threefry, sample position
    const unsigned flat = (unsigned)ray * 64u + (unsigned)lane;
    const unsigned bits = jax_random_bits(flat);
    const float u = __uint_as_float((bits >> 9) | 0x3f800000u) - 1.0f;
    float t = tmin + u * (tmax - tmin);

    // Bitonic sort ascending across the 64 lanes of the wave
#pragma unroll
    for (int k = 2; k <= 64; k <<= 1) {
#pragma unroll
        for (int j = k >> 1; j > 0; j >>= 1) {
            float p = __shfl_xor(t, j, 64);
            bool up = ((lane & k) == 0);
            bool lower = ((lane & j) == 0);
            t = (up == lower) ? fminf(t, p) : fmaxf(t, p);
        }
    }

    const float tnext = __shfl_down(t, 1, 64);  // garbage at lane 63 (masked later)

    // Sample point + trilerp setup (mirror reference: floor, clip, frac)
    const float px = ox + t * dx, py = oy + t * dy, pz = oz + t * dz;
    float bx = fminf(fmaxf(floorf(px), 0.0f), (float)(IDIM - 1));
    float by = fminf(fmaxf(floorf(py), 0.0f), (float)(IDIM - 1));
    float bz = fminf(fmaxf(floorf(pz), 0.0f), (float)(IDIM - 1));
    const int ix = (int)bx, iy = (int)by, iz = (int)bz;
    const float fx = px - bx, fy = py - by, fz = pz - bz;

    float h = 0.0f, o = 0.0f;
    if (MODE == 2) {
        const uint4* __restrict__ pkq = (const uint4*)table;
        const float wy0 = 1.0f - fy, wy1 = fy, wz0 = 1.0f - fz, wz1 = fz;
        const size_t e0 = ((size_t)ix * GDIM + (size_t)iy) * GDIM + (size_t)iz;
        const uint4 qa = pkq[e0];
        const uint4 qb = pkq[e0 + (size_t)GDIM2];
#pragma unroll
        for (int cx = 0; cx < 2; ++cx) {
            const uint4 q = cx ? qb : qa;
            const float wx = cx ? fx : 1.0f - fx;
            const float w00 = wx * wy0 * wz0, w01 = wx * wy0 * wz1;
            const float w10 = wx * wy1 * wz0, w11 = wx * wy1 * wz1;
            float2 f;
            f = h2f2(q.x); h += w00 * f.x; o += w00 * f.y;
            f = h2f2(q.y); h += w01 * f.x; o += w01 * f.y;
            f = h2f2(q.z); h += w10 * f.x; o += w10 * f.y;
            f = h2f2(q.w); h += w11 * f.x; o += w11 * f.y;
        }
    } else {
#pragma unroll
        for (int c = 0; c < 8; ++c) {
            const int cx = (c >> 2) & 1, cy = (c >> 1) & 1, cz = c & 1;
            const float w = (cx ? fx : 1.0f - fx) * (cy ? fy : 1.0f - fy) * (cz ? fz : 1.0f - fz);
            const size_t idx = ((size_t)(ix + cx) * GDIM + (size_t)(iy + cy)) * GDIM + (size_t)(iz + cz);
            const float* g = grid + idx * 9;
            float s = 0.0f;
#pragma unroll
            for (int ch = 0; ch < 9; ++ch) s += g[ch];
            h += w * s;
            o += w * opac[idx];
        }
    }

    // Transmittance accumulation across the wave
    const float delta = tnext - t;
    const float cur = (lane < 63) ? delta * o : 0.0f;

    float inc = cur;  // inclusive prefix sum
#pragma unroll
    for (int off = 1; off < 64; off <<= 1) {
        float n = __shfl_up(inc, off, 64);
        if (lane >= off) inc += n;
    }
    const float excl = inc - cur;
    const float trans = expf(-excl);
    const float colr = 1.0f / (1.0f + expf(-h));
    float contrib = (lane < 63) ? trans * (1.0f - expf(-cur)) * colr : 0.0f;

#pragma unroll
    for (int off = 32; off > 0; off >>= 1) contrib += __shfl_xor(contrib, off, 64);

    if (lane == 0) out[ray] = contrib;
}

extern "C" void kernel_launch(void* const* d_in, const int* in_sizes, int n_in,
                              void* d_out, int out_size, void* d_ws, size_t ws_size,
                              hipStream_t stream) {
    const float* x = (const float*)d_in[0];
    const float* d = (const float*)d_in[1];
    const float* grid = (const float*)d_in[2];
    const float* opac = (const float*)d_in[3];
    float* out = (float*)d_out;

    const size_t need_quad = (size_t)NCELL * 16;  // ~66.8 MB
    const int waves_per_block = 4;  // 256 threads
    const int nblocks = NB_RAYS / waves_per_block;
    const int fused_blocks = ZT * YT * GDIM;      // 11*11*161 = 19481

    if (ws_size >= need_quad) {
        unsigned* pk = (unsigned*)d_ws;
        rf_fused<<<fused_blocks, 256, 0, stream>>>(grid, opac, pk);
        rf_main<2><<<nblocks, 256, 0, stream>>>(x, d, pk, nullptr, nullptr, out);
    } else {
        rf_main<0><<<nblocks, 256, 0, stream>>>(x, d, nullptr, grid, opac, out);
    }
}